// Round 11
// baseline (221.712 us; speedup 1.0000x reference)
//
#include <hip/hip_runtime.h>
#include <hip/hip_cooperative_groups.h>

namespace cg = cooperative_groups;

#define B_     128
#define S_     256
#define MW_    21
#define VOCAB_ 100
#define EC_    50
#define EW_    256
#define KW_    5
#define T_     17              // MW - K + 1
#define NW_    (B_ * S_)       // 32768 words
#define GROWS  (VOCAB_ * KW_)  // 500
#define WPB    128             // words per mega block

typedef _Float16 f16x8 __attribute__((ext_vector_type(8)));
typedef float    f32x4 __attribute__((ext_vector_type(4)));

// ---------------- fused kernel: prep -> grid.sync -> conv/maxpool -> dual-GEMM highway
// prep: g[v*5+k][o] = sum_i emb[v][i]*cw[o][i][k] (fp16), one elem/thread;
//       Wp/Wg f32 -> fp16 MFMA-B-fragment order on threads 0..8191.
// phase A/B identical to round-10 k_mega (conflict-minimal stride-64 g_s,
// XOR-swizzled y_s fragment granules, register-prefetch g staging).
__global__ __launch_bounds__(512, 2) void k_fused(const int* __restrict__ idx,
                                                  const float* __restrict__ emb,
                                                  const float* __restrict__ cw,
                                                  const float* __restrict__ cb,
                                                  const float* __restrict__ Wp,
                                                  const float* __restrict__ bp,
                                                  const float* __restrict__ Wg,
                                                  const float* __restrict__ bg,
                                                  float* __restrict__ out,
                                                  _Float16* __restrict__ gws,
                                                  _Float16* __restrict__ wpf,
                                                  _Float16* __restrict__ wgf) {
  __shared__ __align__(16) _Float16 lds[32768 + GROWS * 64];
  _Float16* y_s = lds;            // 32768 halves: (frag*64 + (lane_t^og)) * 8 + j
  _Float16* g_s = lds + 32768;    // [500][64]

  const int tid  = threadIdx.x;
  const int wave = tid >> 6, lane = tid & 63;
  const int m0 = blockIdx.x * WPB;
  const int wq = lane >> 3, og = lane & 7;

  // ======== prep phase (distributed across the grid) ========
  const int gtid = blockIdx.x * 512 + tid;
  if (gtid < GROWS * EW_) {                       // 128000 g-table elems
    const int row = gtid >> 8;                    // v*5+k
    const int o   = gtid & 255;
    const int v   = (row * 205) >> 10;            // row/5 (exact for row<500)
    const int k   = row - v * KW_;
    const float* __restrict__ er = emb + v * EC_;
    const float* __restrict__ wr = cw + (o * EC_) * KW_ + k;
    float acc = 0.f;
#pragma unroll
    for (int i = 0; i < EC_; ++i) acc += er[i] * wr[i * KW_];
    gws[gtid] = (_Float16)acc;
  }
  if (gtid < 8192) {                              // weight frag conversion
    const int fl  = gtid;
    const int nt  = fl >> 9;
    const int rem = fl & 511;
    const int ks  = rem >> 6;
    const int l   = rem & 63;
    const int n   = nt * 16 + (l & 15);
    const int kc  = ks * 32 + (l >> 4) * 8;
    const int src = n * EW_ + kc;
    const float4 p0 = *(const float4*)&Wp[src], p1 = *(const float4*)&Wp[src + 4];
    const float4 q0 = *(const float4*)&Wg[src], q1 = *(const float4*)&Wg[src + 4];
    f16x8 hp = {(_Float16)p0.x, (_Float16)p0.y, (_Float16)p0.z, (_Float16)p0.w,
                (_Float16)p1.x, (_Float16)p1.y, (_Float16)p1.z, (_Float16)p1.w};
    f16x8 hg = {(_Float16)q0.x, (_Float16)q0.y, (_Float16)q0.z, (_Float16)q0.w,
                (_Float16)q1.x, (_Float16)q1.y, (_Float16)q1.z, (_Float16)q1.w};
    *(f16x8*)&wpf[fl * 8] = hp;
    *(f16x8*)&wgf[fl * 8] = hg;
  }
  __threadfence();
  cg::this_grid().sync();

  // ======== phase A: conv + relu + maxpool -> y_s fragments ========
  // initial stage: chunk 0
#pragma unroll
  for (int i = 0; i < 8; ++i) {
    const int c = tid + i * 512;
    if (c < GROWS * 8) {
      const int row = c >> 3, cc = c & 7;
      *(f16x8*)&g_s[row * 64 + cc * 8] = *(const f16x8*)&gws[row * EW_ + cc * 8];
    }
  }
  __syncthreads();

  f16x8 pre[8];
#pragma unroll
  for (int chunk = 0; chunk < 4; ++chunk) {
    const int oc0 = chunk * 64;
    if (chunk < 3) {
#pragma unroll
      for (int i = 0; i < 8; ++i) {
        const int c = tid + i * 512;
        if (c < GROWS * 8) {
          const int row = c >> 3, cc = c & 7;
          pre[i] = *(const f16x8*)&gws[row * EW_ + oc0 + 64 + cc * 8];
        }
      }
    }

    f16x8 bias;
#pragma unroll
    for (int j = 0; j < 8; ++j) bias[j] = (_Float16)cb[oc0 + og * 8 + j];

    const int ks_w    = chunk * 2 + (og >> 2);
    const int lane_hi = (og & 3) << 4;

#pragma unroll
    for (int it = 0; it < 2; ++it) {
      const int wl = it * 64 + wave * 8 + wq;
      const int* __restrict__ ip = idx + (m0 + wl) * MW_;
      int base[MW_];
#pragma unroll
      for (int c = 0; c < MW_; ++c)
        base[c] = ip[c] * (KW_ * 64) + og * 8;

      const _Float16 NEG = (_Float16)(-60000.0f);
      f16x8 mx = {NEG, NEG, NEG, NEG, NEG, NEG, NEG, NEG};
#pragma unroll
      for (int t = 0; t < T_; ++t) {
        f16x8 s = *(const f16x8*)&g_s[base[t]];              // k = 0
#pragma unroll
        for (int k = 1; k < KW_; ++k)
          s += *(const f16x8*)&g_s[base[t + k] + k * 64];    // v_pk_add_f16
        mx = __builtin_elementwise_max(mx, s);               // v_pk_max_f16
      }
      // relu(bias + max_t s) == max_t relu(bias + s)
      const f16x8 zero8 = {0, 0, 0, 0, 0, 0, 0, 0};
      mx = __builtin_elementwise_max(mx + bias, zero8);

      const int mt = wl >> 4;
      const int lt = ((wl & 15) | lane_hi) ^ og;             // swizzled granule low-6
      *(f16x8*)&y_s[((mt * 8 + ks_w) * 64 + lt) * 8] = mx;
    }
    __syncthreads();
    if (chunk < 3) {
#pragma unroll
      for (int i = 0; i < 8; ++i) {
        const int c = tid + i * 512;
        if (c < GROWS * 8) {
          const int row = c >> 3, cc = c & 7;
          *(f16x8*)&g_s[row * 64 + cc * 8] = pre[i];
        }
      }
      __syncthreads();
    }
  }

  // ======== phase B: dual GEMM + highway — B streamed from L2, no barriers ========
  const int mtp = wave >> 1, nh = wave & 1;
  const int quad = lane >> 4, r16 = lane & 15;

  f16x8 a[2][8];
#pragma unroll
  for (int mi = 0; mi < 2; ++mi)
#pragma unroll
    for (int ks = 0; ks < 8; ++ks) {
      const int key = ((ks & 1) << 2) | quad;                // == writer og
      a[mi][ks] = *(const f16x8*)&y_s[(((mtp * 2 + mi) * 8 + ks) * 64 + (lane ^ key)) * 8];
    }

  const f32x4 zero = {0.f, 0.f, 0.f, 0.f};
#pragma unroll
  for (int h = 0; h < 2; ++h) {
    f32x4 accp[2][4], accg[2][4];
#pragma unroll
    for (int mi = 0; mi < 2; ++mi)
#pragma unroll
      for (int nf = 0; nf < 4; ++nf) { accp[mi][nf] = zero; accg[mi][nf] = zero; }

#pragma unroll
    for (int nf = 0; nf < 4; ++nf) {
      const int nt = h * 8 + nh * 4 + nf;
#pragma unroll
      for (int ks = 0; ks < 8; ++ks) {
        const int off = ((nt * 8 + ks) * 64 + lane) * 8;
        const f16x8 bpv = *(const f16x8*)&wpf[off];
        const f16x8 bgv = *(const f16x8*)&wgf[off];
#pragma unroll
        for (int mi = 0; mi < 2; ++mi) {
          accp[mi][nf] = __builtin_amdgcn_mfma_f32_16x16x32_f16(a[mi][ks], bpv, accp[mi][nf], 0, 0, 0);
          accg[mi][nf] = __builtin_amdgcn_mfma_f32_16x16x32_f16(a[mi][ks], bgv, accg[mi][nf], 0, 0, 0);
        }
      }
    }

#pragma unroll
    for (int mi = 0; mi < 2; ++mi) {
      const int mt = mtp * 2 + mi;
#pragma unroll
      for (int nf = 0; nf < 4; ++nf) {
        const int n = h * 128 + nh * 64 + nf * 16 + r16;
        const float bpn = bp[n];
        const float bgn = bg[n];
        const int ks_e = n >> 5;
        const int lane_e = ((n >> 3) & 3) << 4;
        const int og_e = (n >> 3) & 7;
        const int je = n & 7;
#pragma unroll
        for (int reg = 0; reg < 4; ++reg) {
          const int m = mt * 16 + quad * 4 + reg;
          float p = fmaxf(accp[mi][nf][reg] + bpn, 0.f);
          const float gz = accg[mi][nf][reg] + bgn;
          const float gate = 1.f / (1.f + __expf(-gz));
          const float yv =
              (float)y_s[((mt * 8 + ks_e) * 64 + (((m & 15) | lane_e) ^ og_e)) * 8 + je];
          out[(m0 + m) * EW_ + n] = gate * p + (1.f - gate) * yv;
        }
      }
    }
  }
}

extern "C" void kernel_launch(void* const* d_in, const int* in_sizes, int n_in,
                              void* d_out, int out_size, void* d_ws, size_t ws_size,
                              hipStream_t stream) {
  (void)in_sizes; (void)n_in; (void)out_size; (void)ws_size;
  const int*   idx = (const int*)d_in[0];
  const float* emb = (const float*)d_in[1];
  const float* cw  = (const float*)d_in[2];
  const float* cb  = (const float*)d_in[3];
  const float* wp  = (const float*)d_in[4];
  const float* bpp = (const float*)d_in[5];
  const float* wgt = (const float*)d_in[6];
  const float* bgg = (const float*)d_in[7];
  float* out = (float*)d_out;
  _Float16* g_ws = (_Float16*)d_ws;            // 500*256 fp16
  _Float16* wp_f = g_ws + GROWS * EW_;         // 65536 halves, frag order
  _Float16* wg_f = wp_f + EW_ * EW_;           // 65536 halves, frag order

  void* args[] = {(void*)&idx, (void*)&emb, (void*)&cw, (void*)&cb,
                  (void*)&wp,  (void*)&bpp, (void*)&wgt, (void*)&bgg,
                  (void*)&out, (void*)&g_ws, (void*)&wp_f, (void*)&wg_f};
  hipLaunchCooperativeKernel((const void*)k_fused, dim3(NW_ / WPB), dim3(512),
                             args, 0, stream);
}

// Round 12
// 126.926 us; speedup vs baseline: 1.7468x; 1.7468x over previous
//
#include <hip/hip_runtime.h>

#define B_     128
#define S_     256
#define MW_    21
#define VOCAB_ 100
#define EC_    50
#define EW_    256
#define KW_    5
#define T_     17              // MW - K + 1
#define NW_    (B_ * S_)       // 32768 words
#define GROWS  (VOCAB_ * KW_)  // 500
#define WPB    128             // words per mega block

typedef _Float16 f16x8 __attribute__((ext_vector_type(8)));
typedef float    f32x4 __attribute__((ext_vector_type(4)));

// ---------------- kernel 1: prep
// blocks [0,500): g[v*5+k][o] = sum_i emb[v][i]*conv_w[o][i][k]  (fp16, row-major [500][256])
// blocks [500,532): Wp/Wg f32 -> fp16 in MFMA B-fragment order:
//   frag f = nt*8+ks, lane l holds W[nt*16+(l&15)][ks*32+(l>>4)*8 + j]
__global__ __launch_bounds__(256) void k_prep(const float* __restrict__ emb,
                                              const float* __restrict__ cw,
                                              const float* __restrict__ Wp,
                                              const float* __restrict__ Wg,
                                              _Float16* __restrict__ g,
                                              _Float16* __restrict__ wpf,
                                              _Float16* __restrict__ wgf) {
  const int bi = blockIdx.x;
  if (bi < GROWS) {
    __shared__ float es[EC_];
    const int v = bi / KW_;
    const int k = bi % KW_;
    const int o = threadIdx.x;
    if (threadIdx.x < EC_) es[threadIdx.x] = emb[v * EC_ + threadIdx.x];
    __syncthreads();
    float acc = 0.f;
#pragma unroll
    for (int i = 0; i < EC_; ++i)
      acc += es[i] * cw[(o * EC_ + i) * KW_ + k];
    g[bi * EW_ + o] = (_Float16)acc;
  } else {
    const int fl  = (bi - GROWS) * 256 + threadIdx.x;  // 0..8191 lane-frags
    const int nt  = fl >> 9;
    const int rem = fl & 511;
    const int ks  = rem >> 6;
    const int l   = rem & 63;
    const int n   = nt * 16 + (l & 15);
    const int kc  = ks * 32 + (l >> 4) * 8;
    const int src = n * EW_ + kc;
    const float4 p0 = *(const float4*)&Wp[src], p1 = *(const float4*)&Wp[src + 4];
    const float4 q0 = *(const float4*)&Wg[src], q1 = *(const float4*)&Wg[src + 4];
    f16x8 hp = {(_Float16)p0.x, (_Float16)p0.y, (_Float16)p0.z, (_Float16)p0.w,
                (_Float16)p1.x, (_Float16)p1.y, (_Float16)p1.z, (_Float16)p1.w};
    f16x8 hg = {(_Float16)q0.x, (_Float16)q0.y, (_Float16)q0.z, (_Float16)q0.w,
                (_Float16)q1.x, (_Float16)q1.y, (_Float16)q1.z, (_Float16)q1.w};
    *(f16x8*)&wpf[fl * 8] = hp;
    *(f16x8*)&wgf[fl * 8] = hg;
  }
}

// ---------------- kernel 2: mega — conv+relu+maxpool (A) + dual-GEMM highway (B)
// 1024 threads (16 waves), WPB=128: each chunk's 1024 word-octets gathered in ONE
// parallel sweep (no serialized it-pair). LDS = y_s 65536 + g_s 64000 + idx_s 10752
// = 140288 B, 1 block/CU. g_s plain stride-64 (empirically minimal conflicts);
// y_s XOR-og granule swizzle (R10-verified); g staged via register prefetch.
__global__ __launch_bounds__(1024, 4) void k_mega(const int* __restrict__ idx,
                                                  const _Float16* __restrict__ g,
                                                  const float* __restrict__ cb,
                                                  const _Float16* __restrict__ wpf,
                                                  const _Float16* __restrict__ wgf,
                                                  const float* __restrict__ bp,
                                                  const float* __restrict__ bg,
                                                  float* __restrict__ out) {
  __shared__ __align__(16) _Float16 lds[32768 + GROWS * 64];
  __shared__ int idx_s[WPB * MW_];     // premultiplied by KW_*64
  _Float16* y_s = lds;                 // 32768 halves: (frag*64 + (lane_t^og)) * 8 + j
  _Float16* g_s = lds + 32768;         // [500][64]

  const int tid  = threadIdx.x;
  const int wave = tid >> 6, lane = tid & 63;
  const int m0 = blockIdx.x * WPB;
  const int wq = lane >> 3, og = lane & 7;

  // stage idx once (premultiplied row offset)
  for (int c = tid; c < WPB * MW_; c += 1024)
    idx_s[c] = idx[m0 * MW_ + c] * (KW_ * 64);

  // initial stage: chunk 0
#pragma unroll
  for (int i = 0; i < 4; ++i) {
    const int c = tid + i * 1024;
    if (c < GROWS * 8) {
      const int row = c >> 3, cc = c & 7;
      *(f16x8*)&g_s[row * 64 + cc * 8] = *(const f16x8*)&g[row * EW_ + cc * 8];
    }
  }
  __syncthreads();

  f16x8 pre[4];
#pragma unroll
  for (int chunk = 0; chunk < 4; ++chunk) {
    const int oc0 = chunk * 64;
    // issue next chunk's loads into registers (no vmcnt drain at the barrier)
    if (chunk < 3) {
#pragma unroll
      for (int i = 0; i < 4; ++i) {
        const int c = tid + i * 1024;
        if (c < GROWS * 8) {
          const int row = c >> 3, cc = c & 7;
          pre[i] = *(const f16x8*)&g[row * EW_ + oc0 + 64 + cc * 8];
        }
      }
    }

    f16x8 bias;
#pragma unroll
    for (int j = 0; j < 8; ++j) bias[j] = (_Float16)cb[oc0 + og * 8 + j];

    const int ks_w    = chunk * 2 + (og >> 2);
    const int lane_hi = (og & 3) << 4;

    const int wl = wave * 8 + wq;                 // word 0..127, one sweep
    const int* __restrict__ ip = idx_s + wl * MW_;
    int base[MW_];
#pragma unroll
    for (int c = 0; c < MW_; ++c)
      base[c] = ip[c] + og * 8;                   // broadcast LDS read + add

    const _Float16 NEG = (_Float16)(-60000.0f);
    f16x8 mx = {NEG, NEG, NEG, NEG, NEG, NEG, NEG, NEG};
#pragma unroll
    for (int t = 0; t < T_; ++t) {
      f16x8 s = *(const f16x8*)&g_s[base[t]];              // k = 0
#pragma unroll
      for (int k = 1; k < KW_; ++k)
        s += *(const f16x8*)&g_s[base[t + k] + k * 64];    // v_pk_add_f16
      mx = __builtin_elementwise_max(mx, s);               // v_pk_max_f16
    }
    // relu(bias + max_t s) == max_t relu(bias + s)
    const f16x8 zero8 = {0, 0, 0, 0, 0, 0, 0, 0};
    mx = __builtin_elementwise_max(mx + bias, zero8);

    const int mt = wl >> 4;
    const int lt = ((wl & 15) | lane_hi) ^ og;             // swizzled granule low-6
    *(f16x8*)&y_s[((mt * 8 + ks_w) * 64 + lt) * 8] = mx;

    __syncthreads();  // gather(c)+y-writes complete; g_s free
    if (chunk < 3) {
#pragma unroll
      for (int i = 0; i < 4; ++i) {
        const int c = tid + i * 1024;
        if (c < GROWS * 8) {
          const int row = c >> 3, cc = c & 7;
          *(f16x8*)&g_s[row * 64 + cc * 8] = pre[i];
        }
      }
      __syncthreads();
    }
  }

  // ======== phase B: dual GEMM + highway — B streamed from L2, no barriers ========
  // 16 waves: mtp = wave>>2 (pair of m-tiles), nq = wave&3 (n-quarter, 64 cols).
  // Per-wave weight loads: 4nf*8ks*2mat*1KB = 64KB -> 1MB/block (same as R10).
  const int mtp = wave >> 2, nq = wave & 3;
  const int quad = lane >> 4, r16 = lane & 15;

  f16x8 a[2][8];
#pragma unroll
  for (int mi = 0; mi < 2; ++mi)
#pragma unroll
    for (int ks = 0; ks < 8; ++ks) {
      const int key = ((ks & 1) << 2) | quad;              // == writer og
      a[mi][ks] = *(const f16x8*)&y_s[(((mtp * 2 + mi) * 8 + ks) * 64 + (lane ^ key)) * 8];
    }

  const f32x4 zero = {0.f, 0.f, 0.f, 0.f};
  f32x4 accp[2][4], accg[2][4];
#pragma unroll
  for (int mi = 0; mi < 2; ++mi)
#pragma unroll
    for (int nf = 0; nf < 4; ++nf) { accp[mi][nf] = zero; accg[mi][nf] = zero; }

#pragma unroll
  for (int nf = 0; nf < 4; ++nf) {
    const int nt = nq * 4 + nf;
#pragma unroll
    for (int ks = 0; ks < 8; ++ks) {
      const int off = ((nt * 8 + ks) * 64 + lane) * 8;
      const f16x8 bpv = *(const f16x8*)&wpf[off];
      const f16x8 bgv = *(const f16x8*)&wgf[off];
#pragma unroll
      for (int mi = 0; mi < 2; ++mi) {
        accp[mi][nf] = __builtin_amdgcn_mfma_f32_16x16x32_f16(a[mi][ks], bpv, accp[mi][nf], 0, 0, 0);
        accg[mi][nf] = __builtin_amdgcn_mfma_f32_16x16x32_f16(a[mi][ks], bgv, accg[mi][nf], 0, 0, 0);
      }
    }
  }

  // epilogue
#pragma unroll
  for (int mi = 0; mi < 2; ++mi) {
    const int mt = mtp * 2 + mi;
#pragma unroll
    for (int nf = 0; nf < 4; ++nf) {
      const int n = nq * 64 + nf * 16 + r16;
      const float bpn = bp[n];
      const float bgn = bg[n];
      const int ks_e = n >> 5;
      const int lane_e = ((n >> 3) & 3) << 4;
      const int og_e = (n >> 3) & 7;
      const int je = n & 7;
#pragma unroll
      for (int reg = 0; reg < 4; ++reg) {
        const int m = mt * 16 + quad * 4 + reg;
        float p = fmaxf(accp[mi][nf][reg] + bpn, 0.f);
        const float gz = accg[mi][nf][reg] + bgn;
        const float gate = 1.f / (1.f + __expf(-gz));
        const float yv =
            (float)y_s[((mt * 8 + ks_e) * 64 + (((m & 15) | lane_e) ^ og_e)) * 8 + je];
        out[(m0 + m) * EW_ + n] = gate * p + (1.f - gate) * yv;
      }
    }
  }
}

extern "C" void kernel_launch(void* const* d_in, const int* in_sizes, int n_in,
                              void* d_out, int out_size, void* d_ws, size_t ws_size,
                              hipStream_t stream) {
  (void)in_sizes; (void)n_in; (void)out_size; (void)ws_size;
  const int*   idx = (const int*)d_in[0];
  const float* emb = (const float*)d_in[1];
  const float* cw  = (const float*)d_in[2];
  const float* cb  = (const float*)d_in[3];
  const float* wp  = (const float*)d_in[4];
  const float* bpp = (const float*)d_in[5];
  const float* wgt = (const float*)d_in[6];
  const float* bgg = (const float*)d_in[7];
  float* out = (float*)d_out;
  _Float16* g_ws = (_Float16*)d_ws;            // 500*256 fp16
  _Float16* wp_f = g_ws + GROWS * EW_;         // 65536 halves, frag order
  _Float16* wg_f = wp_f + EW_ * EW_;           // 65536 halves, frag order

  k_prep<<<GROWS + 32, 256, 0, stream>>>(emb, cw, wp, wgt, g_ws, wp_f, wg_f);
  k_mega<<<NW_ / WPB, 1024, 0, stream>>>(idx, g_ws, cb, wp_f, wg_f, bpp, bgg, out);
}

// Round 13
// 125.504 us; speedup vs baseline: 1.7666x; 1.0113x over previous
//
#include <hip/hip_runtime.h>

#define B_     128
#define S_     256
#define MW_    21
#define VOCAB_ 100
#define EC_    50
#define EW_    256
#define KW_    5
#define T_     17              // MW - K + 1
#define NW_    (B_ * S_)       // 32768 words
#define GROWS  (VOCAB_ * KW_)  // 500
#define WPB    128             // words per mega block

typedef _Float16 f16x8 __attribute__((ext_vector_type(8)));
typedef float    f32x4 __attribute__((ext_vector_type(4)));

// ---------------- kernel 1: prep
// blocks [0,500): g[v*5+k][o] = sum_i emb[v][i]*conv_w[o][i][k]  (fp16, row-major [500][256])
// blocks [500,532): Wp/Wg f32 -> fp16 in MFMA B-fragment order:
//   frag f = nt*8+ks, lane l holds W[nt*16+(l&15)][ks*32+(l>>4)*8 + j]
__global__ __launch_bounds__(256) void k_prep(const float* __restrict__ emb,
                                              const float* __restrict__ cw,
                                              const float* __restrict__ Wp,
                                              const float* __restrict__ Wg,
                                              _Float16* __restrict__ g,
                                              _Float16* __restrict__ wpf,
                                              _Float16* __restrict__ wgf) {
  const int bi = blockIdx.x;
  if (bi < GROWS) {
    __shared__ float es[EC_];
    const int v = bi / KW_;
    const int k = bi % KW_;
    const int o = threadIdx.x;
    if (threadIdx.x < EC_) es[threadIdx.x] = emb[v * EC_ + threadIdx.x];
    __syncthreads();
    float acc = 0.f;
#pragma unroll
    for (int i = 0; i < EC_; ++i)
      acc += es[i] * cw[(o * EC_ + i) * KW_ + k];
    g[bi * EW_ + o] = (_Float16)acc;
  } else {
    const int fl  = (bi - GROWS) * 256 + threadIdx.x;  // 0..8191 lane-frags
    const int nt  = fl >> 9;
    const int rem = fl & 511;
    const int ks  = rem >> 6;
    const int l   = rem & 63;
    const int n   = nt * 16 + (l & 15);
    const int kc  = ks * 32 + (l >> 4) * 8;
    const int src = n * EW_ + kc;
    const float4 p0 = *(const float4*)&Wp[src], p1 = *(const float4*)&Wp[src + 4];
    const float4 q0 = *(const float4*)&Wg[src], q1 = *(const float4*)&Wg[src + 4];
    f16x8 hp = {(_Float16)p0.x, (_Float16)p0.y, (_Float16)p0.z, (_Float16)p0.w,
                (_Float16)p1.x, (_Float16)p1.y, (_Float16)p1.z, (_Float16)p1.w};
    f16x8 hg = {(_Float16)q0.x, (_Float16)q0.y, (_Float16)q0.z, (_Float16)q0.w,
                (_Float16)q1.x, (_Float16)q1.y, (_Float16)q1.z, (_Float16)q1.w};
    *(f16x8*)&wpf[fl * 8] = hp;
    *(f16x8*)&wgf[fl * 8] = hg;
  }
}

// ---------------- kernel 2: mega — conv+relu+maxpool (A) + dual-GEMM highway (B)
// 1024 threads (16 waves), WPB=128: each chunk's 1024 word-octets gathered in ONE
// parallel sweep. LDS = y_s 65536 + g_s 64000 + idx_s 10752 = 140288 B, 1 block/CU.
// __launch_bounds__(1024) with NO second arg: the mandatory 4-waves/EU fit caps
// VGPR at 128 (R12's (1024,4) forced a 64-VGPR clamp -> 16 MB scratch spill).
__global__ __launch_bounds__(1024) void k_mega(const int* __restrict__ idx,
                                               const _Float16* __restrict__ g,
                                               const float* __restrict__ cb,
                                               const _Float16* __restrict__ wpf,
                                               const _Float16* __restrict__ wgf,
                                               const float* __restrict__ bp,
                                               const float* __restrict__ bg,
                                               float* __restrict__ out) {
  __shared__ __align__(16) _Float16 lds[32768 + GROWS * 64];
  __shared__ int idx_s[WPB * MW_];     // premultiplied by KW_*64
  _Float16* y_s = lds;                 // 32768 halves: (frag*64 + (lane_t^og)) * 8 + j
  _Float16* g_s = lds + 32768;         // [500][64]

  const int tid  = threadIdx.x;
  const int wave = tid >> 6, lane = tid & 63;
  const int m0 = blockIdx.x * WPB;
  const int wq = lane >> 3, og = lane & 7;

  // stage idx once (premultiplied row offset)
  for (int c = tid; c < WPB * MW_; c += 1024)
    idx_s[c] = idx[m0 * MW_ + c] * (KW_ * 64);

  // initial stage: chunk 0
#pragma unroll
  for (int i = 0; i < 4; ++i) {
    const int c = tid + i * 1024;
    if (c < GROWS * 8) {
      const int row = c >> 3, cc = c & 7;
      *(f16x8*)&g_s[row * 64 + cc * 8] = *(const f16x8*)&g[row * EW_ + cc * 8];
    }
  }
  __syncthreads();

  f16x8 pre[4];
#pragma unroll
  for (int chunk = 0; chunk < 4; ++chunk) {
    const int oc0 = chunk * 64;
    // issue next chunk's loads into registers (no vmcnt drain at the barrier)
    if (chunk < 3) {
#pragma unroll
      for (int i = 0; i < 4; ++i) {
        const int c = tid + i * 1024;
        if (c < GROWS * 8) {
          const int row = c >> 3, cc = c & 7;
          pre[i] = *(const f16x8*)&g[row * EW_ + oc0 + 64 + cc * 8];
        }
      }
    }

    f16x8 bias;
#pragma unroll
    for (int j = 0; j < 8; ++j) bias[j] = (_Float16)cb[oc0 + og * 8 + j];

    const int ks_w    = chunk * 2 + (og >> 2);
    const int lane_hi = (og & 3) << 4;

    const int wl = wave * 8 + wq;                 // word 0..127, one sweep
    const int* __restrict__ ip = idx_s + wl * MW_;
    int base[MW_];
#pragma unroll
    for (int c = 0; c < MW_; ++c)
      base[c] = ip[c] + og * 8;                   // broadcast LDS read + add

    const _Float16 NEG = (_Float16)(-60000.0f);
    f16x8 mx = {NEG, NEG, NEG, NEG, NEG, NEG, NEG, NEG};
#pragma unroll
    for (int t = 0; t < T_; ++t) {
      f16x8 s = *(const f16x8*)&g_s[base[t]];              // k = 0
#pragma unroll
      for (int k = 1; k < KW_; ++k)
        s += *(const f16x8*)&g_s[base[t + k] + k * 64];    // v_pk_add_f16
      mx = __builtin_elementwise_max(mx, s);               // v_pk_max_f16
    }
    // relu(bias + max_t s) == max_t relu(bias + s)
    const f16x8 zero8 = {0, 0, 0, 0, 0, 0, 0, 0};
    mx = __builtin_elementwise_max(mx + bias, zero8);

    const int mt = wl >> 4;
    const int lt = ((wl & 15) | lane_hi) ^ og;             // swizzled granule low-6
    *(f16x8*)&y_s[((mt * 8 + ks_w) * 64 + lt) * 8] = mx;

    __syncthreads();  // gather(c)+y-writes complete; g_s free
    if (chunk < 3) {
#pragma unroll
      for (int i = 0; i < 4; ++i) {
        const int c = tid + i * 1024;
        if (c < GROWS * 8) {
          const int row = c >> 3, cc = c & 7;
          *(f16x8*)&g_s[row * 64 + cc * 8] = pre[i];
        }
      }
      __syncthreads();
    }
  }

  // ======== phase B: dual GEMM + highway — B streamed from L2, no barriers ========
  // 16 waves: mtp = wave>>2 (pair of m-tiles), nq = wave&3 (n-quarter, 64 cols).
  const int mtp = wave >> 2, nq = wave & 3;
  const int quad = lane >> 4, r16 = lane & 15;

  f16x8 a[2][8];
#pragma unroll
  for (int mi = 0; mi < 2; ++mi)
#pragma unroll
    for (int ks = 0; ks < 8; ++ks) {
      const int key = ((ks & 1) << 2) | quad;              // == writer og
      a[mi][ks] = *(const f16x8*)&y_s[(((mtp * 2 + mi) * 8 + ks) * 64 + (lane ^ key)) * 8];
    }

  const f32x4 zero = {0.f, 0.f, 0.f, 0.f};
  f32x4 accp[2][4], accg[2][4];
#pragma unroll
  for (int mi = 0; mi < 2; ++mi)
#pragma unroll
    for (int nf = 0; nf < 4; ++nf) { accp[mi][nf] = zero; accg[mi][nf] = zero; }

#pragma unroll
  for (int nf = 0; nf < 4; ++nf) {
    const int nt = nq * 4 + nf;
#pragma unroll
    for (int ks = 0; ks < 8; ++ks) {
      const int off = ((nt * 8 + ks) * 64 + lane) * 8;
      const f16x8 bpv = *(const f16x8*)&wpf[off];
      const f16x8 bgv = *(const f16x8*)&wgf[off];
#pragma unroll
      for (int mi = 0; mi < 2; ++mi) {
        accp[mi][nf] = __builtin_amdgcn_mfma_f32_16x16x32_f16(a[mi][ks], bpv, accp[mi][nf], 0, 0, 0);
        accg[mi][nf] = __builtin_amdgcn_mfma_f32_16x16x32_f16(a[mi][ks], bgv, accg[mi][nf], 0, 0, 0);
      }
    }
  }

  // epilogue
#pragma unroll
  for (int mi = 0; mi < 2; ++mi) {
    const int mt = mtp * 2 + mi;
#pragma unroll
    for (int nf = 0; nf < 4; ++nf) {
      const int n = nq * 64 + nf * 16 + r16;
      const float bpn = bp[n];
      const float bgn = bg[n];
      const int ks_e = n >> 5;
      const int lane_e = ((n >> 3) & 3) << 4;
      const int og_e = (n >> 3) & 7;
      const int je = n & 7;
#pragma unroll
      for (int reg = 0; reg < 4; ++reg) {
        const int m = mt * 16 + quad * 4 + reg;
        float p = fmaxf(accp[mi][nf][reg] + bpn, 0.f);
        const float gz = accg[mi][nf][reg] + bgn;
        const float gate = 1.f / (1.f + __expf(-gz));
        const float yv =
            (float)y_s[((mt * 8 + ks_e) * 64 + (((m & 15) | lane_e) ^ og_e)) * 8 + je];
        out[(m0 + m) * EW_ + n] = gate * p + (1.f - gate) * yv;
      }
    }
  }
}

extern "C" void kernel_launch(void* const* d_in, const int* in_sizes, int n_in,
                              void* d_out, int out_size, void* d_ws, size_t ws_size,
                              hipStream_t stream) {
  (void)in_sizes; (void)n_in; (void)out_size; (void)ws_size;
  const int*   idx = (const int*)d_in[0];
  const float* emb = (const float*)d_in[1];
  const float* cw  = (const float*)d_in[2];
  const float* cb  = (const float*)d_in[3];
  const float* wp  = (const float*)d_in[4];
  const float* bpp = (const float*)d_in[5];
  const float* wgt = (const float*)d_in[6];
  const float* bgg = (const float*)d_in[7];
  float* out = (float*)d_out;
  _Float16* g_ws = (_Float16*)d_ws;            // 500*256 fp16
  _Float16* wp_f = g_ws + GROWS * EW_;         // 65536 halves, frag order
  _Float16* wg_f = wp_f + EW_ * EW_;           // 65536 halves, frag order

  k_prep<<<GROWS + 32, 256, 0, stream>>>(emb, cw, wp, wgt, g_ws, wp_f, wg_f);
  k_mega<<<NW_ / WPB, 1024, 0, stream>>>(idx, g_ws, cb, wp_f, wg_f, bpp, bgg, out);
}